// Round 14
// baseline (276.477 us; speedup 1.0000x reference)
//
#include <hip/hip_runtime.h>
#include <cmath>

namespace {

constexpr int BATCH = 256;
// layer 1
constexpr int C1 = 3, H1 = 218, W1 = 178;
constexpr int IMG1 = C1 * H1 * W1;            // 116412
constexpr int PLANE1 = H1 * W1;               // 38804
constexpr int O1 = 8, HO1 = 54, WO1 = 44;
constexpr int HW1 = HO1 * WO1;                // 2376
constexpr int P1 = C1 * 36;                   // 108
// layer 2
constexpr int C2 = 8, H2c = 54, W2c = 44;
constexpr int O2 = 16, HO2 = 13, WO2 = 10;
constexpr int HW2 = HO2 * WO2;                // 130
constexpr int P2 = C2 * 36;                   // 288
// head
constexpr int NPOOL = 480;                    // 16*6*5
constexpr int N1 = 300, N2 = 200;

// lc1: block = 16 hw x 64 batches, 512 thr (8 waves), BJ=2 batches/thread.
// w slice LDS-resident with padded p-stride (132 words) so staging writes
// are 4-way not 16-way bank-conflicted; compute reads stay conflict-free.
constexpr int THW = 16;
constexpr int NBB = 64;
constexpr int BJ = 2;
constexpr int PSTR = 132;                     // words per p (128 + 4 pad)

// ---- transpose w2 (O2,P2,HW2) -> (P2*HW2, O2)
__global__ __launch_bounds__(256) void wt2_kernel(const float* __restrict__ w,
                                                  float* __restrict__ wt) {
  const int idx = blockIdx.x * 256 + threadIdx.x;   // p*HW2 + hw
  if (idx >= P2 * HW2) return;
  float v[O2];
#pragma unroll
  for (int o = 0; o < O2; ++o) v[o] = w[(size_t)o * (P2 * HW2) + idx];
  float4* dst = reinterpret_cast<float4*>(wt + (size_t)idx * O2);
  dst[0] = make_float4(v[0], v[1], v[2], v[3]);
  dst[1] = make_float4(v[4], v[5], v[6], v[7]);
  dst[2] = make_float4(v[8], v[9], v[10], v[11]);
  dst[3] = make_float4(v[12], v[13], v[14], v[15]);
}

// ---- locally-connected layer 1 + ReLU.
// r13 residual diagnosis: VALU ~8us, LDS ~4us, HBM floor ~30us, measured 80
// at VALUBusy 12% -> x-latency exposed with only 2 waves/SIMD and ~400cy
// prefetch distance. Fix: 8 waves (4/SIMD), triple-buffered x (distance 2
// chunks ~1500cy > 900cy HBM), padded LDS stride for staging writes.
__global__ __launch_bounds__(512, 4) void lc1_kernel(const float* __restrict__ x,
                                                     const float* __restrict__ w1,
                                                     const float* __restrict__ b1,
                                                     float* __restrict__ h1t) {
  __shared__ float wl[P1 * PSTR];               // 57024 B -> 2 blocks/CU
  const int t = threadIdx.x;
  const int wave = t >> 6, lane = t & 63;
  const int b2 = lane >> 4, hwl = lane & 15;
  const int hw0 = blockIdx.x * THW;
  const int hw = hw0 + hwl;
  const bool valid = hw < HW1;
  const int hwc = valid ? hw : HW1 - 1;
  const int ho = hwc / WO1, wo = hwc - ho * WO1;
  const int bb = blockIdx.y * NBB + wave * 8 + b2 * BJ;

  // ---- stage the block's full w slice: 108p x 16hw x 8o = 3456 float4 reads
  for (int i = t; i < 3456; i += 512) {
    const int o = i / 432, r = i - o * 432;
    const int p = r >> 2, q = r & 3;
    int hq = hw0 + q * 4;
    if (hq > HW1 - 4) hq = HW1 - 4;             // tail clamp (dup write, benign)
    const float4 wv =
        *reinterpret_cast<const float4*>(w1 + ((size_t)o * P1 + p) * HW1 + hq);
    const int base = p * PSTR + (o >> 1) * 32 + (hq - hw0) * 2 + (o & 1);
    wl[base] = wv.x;
    wl[base + 2] = wv.y;
    wl[base + 4] = wv.z;
    wl[base + 6] = wv.w;
  }

  float acc[BJ][O1];
#pragma unroll
  for (int o = 0; o < O1; ++o) {
    const float bv = b1[o * HW1 + hwc];
#pragma unroll
    for (int j = 0; j < BJ; ++j) acc[j][o] = bv;
  }

  const float* xbase = x + (size_t)bb * IMG1 + (size_t)(ho * 4) * W1 + wo * 4;

  __syncthreads();                              // the ONLY barrier

  float xA[BJ][6], xB[BJ][6], xC[BJ][6];

#define LC1_LD(K, XV)                                                          \
  do {                                                                         \
    const int c_ = (K) / 6, kh_ = (K) - c_ * 6;                                \
    const int xo_ = c_ * PLANE1 + kh_ * W1;                                    \
    _Pragma("unroll") for (int j = 0; j < BJ; ++j) {                           \
      const float* xr = xbase + (size_t)j * IMG1 + xo_;                        \
      const float2 a0 = *reinterpret_cast<const float2*>(xr);                  \
      const float2 a1 = *reinterpret_cast<const float2*>(xr + 2);              \
      const float2 a2 = *reinterpret_cast<const float2*>(xr + 4);              \
      XV[j][0] = a0.x; XV[j][1] = a0.y; XV[j][2] = a1.x;                       \
      XV[j][3] = a1.y; XV[j][4] = a2.x; XV[j][5] = a2.y;                       \
    }                                                                          \
  } while (0)

#define LC1_FMA(K, XV)                                                         \
  do {                                                                         \
    const float2* wb_ = reinterpret_cast<const float2*>(wl);                   \
    _Pragma("unroll") for (int kw = 0; kw < 6; ++kw) {                         \
      const int p_ = (K) * 6 + kw;                                             \
      const float2 w01 = wb_[p_ * (PSTR / 2) + hwl];                           \
      const float2 w23 = wb_[p_ * (PSTR / 2) + 16 + hwl];                      \
      const float2 w45 = wb_[p_ * (PSTR / 2) + 32 + hwl];                      \
      const float2 w67 = wb_[p_ * (PSTR / 2) + 48 + hwl];                      \
      _Pragma("unroll") for (int j = 0; j < BJ; ++j) {                         \
        const float xs = XV[j][kw];                                            \
        acc[j][0] = fmaf(xs, w01.x, acc[j][0]);                                \
        acc[j][1] = fmaf(xs, w01.y, acc[j][1]);                                \
        acc[j][2] = fmaf(xs, w23.x, acc[j][2]);                                \
        acc[j][3] = fmaf(xs, w23.y, acc[j][3]);                                \
        acc[j][4] = fmaf(xs, w45.x, acc[j][4]);                                \
        acc[j][5] = fmaf(xs, w45.y, acc[j][5]);                                \
        acc[j][6] = fmaf(xs, w67.x, acc[j][6]);                                \
        acc[j][7] = fmaf(xs, w67.y, acc[j][7]);                                \
      }                                                                        \
    }                                                                          \
  } while (0)

  // triple-buffer: prefetch distance 2 chunks (~1500 cy wall > HBM latency)
  LC1_LD(0, xA);
  LC1_LD(1, xB);
#pragma unroll 1
  for (int k = 0; k < 18; k += 3) {
    LC1_LD(k + 2, xC);
    __builtin_amdgcn_sched_barrier(0);
    LC1_FMA(k, xA);
    if (k + 3 < 18) LC1_LD(k + 3, xA);
    __builtin_amdgcn_sched_barrier(0);
    LC1_FMA(k + 1, xB);
    if (k + 4 < 18) LC1_LD(k + 4, xB);
    __builtin_amdgcn_sched_barrier(0);
    LC1_FMA(k + 2, xC);
  }
#undef LC1_LD
#undef LC1_FMA

  if (valid) {
#pragma unroll
    for (int o = 0; o < O1; ++o) {
      const float2 v = make_float2(fmaxf(acc[0][o], 0.f), fmaxf(acc[1][o], 0.f));
      *reinterpret_cast<float2*>(h1t + ((size_t)o * HW1 + hw) * BATCH + bb) = v;
    }
  }
}

// ---- locally-connected layer 2 + ReLU, GEMM-ified per spatial location.
// h1t is batch-contiguous (O1,HW1,B) -> coalesced 256B wave reads (r13 win).
__global__ __launch_bounds__(256) void lc2_kernel(const float* __restrict__ h1t,
                                                  const float* __restrict__ w2t,
                                                  const float* __restrict__ b2,
                                                  float* __restrict__ h2) {
  __shared__ float ws[P2 * O2];                 // 18432 B
  const int hw = blockIdx.x;
  const int lane = threadIdx.x & 63;
  const int og = threadIdx.x >> 6;
  const int b = blockIdx.y * 64 + lane;
  const int ho = hw / WO2, wo = hw - ho * WO2;

  for (int i = threadIdx.x; i < P2 * O2; i += 256) {
    const int p = i >> 4, o = i & 15;
    ws[i] = w2t[((size_t)p * HW2 + hw) * O2 + o];
  }
  __syncthreads();

  float acc[4];
#pragma unroll
  for (int oi = 0; oi < 4; ++oi) acc[oi] = b2[(og * 4 + oi) * HW2 + hw];

#pragma unroll 1
  for (int c = 0; c < C2; ++c) {
    const float* bc =
        h1t + ((size_t)(c * H2c + ho * 4) * W2c + wo * 4) * BATCH + b;
    float xv[6][6];
#pragma unroll
    for (int kh = 0; kh < 6; ++kh)
#pragma unroll
      for (int kw = 0; kw < 6; ++kw)
        xv[kh][kw] = bc[(size_t)(kh * W2c + kw) * BATCH];
    __builtin_amdgcn_sched_barrier(0);
#pragma unroll
    for (int kh = 0; kh < 6; ++kh) {
#pragma unroll
      for (int kw = 0; kw < 6; ++kw) {
        const int p = (c * 6 + kh) * 6 + kw;
        const float4 wv = *reinterpret_cast<const float4*>(&ws[p * O2 + og * 4]);
        acc[0] = fmaf(xv[kh][kw], wv.x, acc[0]);
        acc[1] = fmaf(xv[kh][kw], wv.y, acc[1]);
        acc[2] = fmaf(xv[kh][kw], wv.z, acc[2]);
        acc[3] = fmaf(xv[kh][kw], wv.w, acc[3]);
      }
    }
  }

#pragma unroll
  for (int oi = 0; oi < 4; ++oi) {
    h2[((size_t)b * O2 + og * 4 + oi) * HW2 + hw] = fmaxf(acc[oi], 0.f);
  }
}

// ---- fused head: maxpool(2) -> FC1+ReLU -> FC2 -> softmax.
__global__ __launch_bounds__(512) void head_kernel(const float* __restrict__ h2,
                                                   const float* __restrict__ fc1w,
                                                   const float* __restrict__ fc1b,
                                                   const float* __restrict__ fc2w,
                                                   const float* __restrict__ fc2b,
                                                   float* __restrict__ out) {
  __shared__ __align__(16) float sp[NPOOL];
  __shared__ __align__(16) float sh[N1];
  __shared__ float sl[N2];
  __shared__ float red[2];
  const int b = blockIdx.x;
  const int tid = threadIdx.x;

  if (tid < NPOOL) {
    const int o = tid / 30, r2 = tid - o * 30;
    const int i = r2 / 5, j = r2 - i * 5;
    const float* base = h2 + ((size_t)(b * O2 + o) * HO2 + 2 * i) * WO2 + 2 * j;
    sp[tid] = fmaxf(fmaxf(base[0], base[1]), fmaxf(base[WO2], base[WO2 + 1]));
  }
  __syncthreads();

  const int wv = tid >> 6, ln = tid & 63;
  const float4* sp4 = reinterpret_cast<const float4*>(sp);
  for (int n = wv; n < N1; n += 8) {
    const float4* wr = reinterpret_cast<const float4*>(fc1w + (size_t)n * NPOOL);
    float4 a = wr[ln], p = sp4[ln];
    float s = fmaf(a.x, p.x, fmaf(a.y, p.y, fmaf(a.z, p.z, a.w * p.w)));
    if (ln < 56) {
      float4 a2 = wr[64 + ln], p2 = sp4[64 + ln];
      s = fmaf(a2.x, p2.x, fmaf(a2.y, p2.y, fmaf(a2.z, p2.z, fmaf(a2.w, p2.w, s))));
    }
#pragma unroll
    for (int off = 32; off > 0; off >>= 1) s += __shfl_xor(s, off, 64);
    if (ln == 0) sh[n] = fmaxf(s + fc1b[n], 0.f);
  }
  __syncthreads();

  const float4* sh4 = reinterpret_cast<const float4*>(sh);
  for (int n = wv; n < N2; n += 8) {
    const float4* wr = reinterpret_cast<const float4*>(fc2w + (size_t)n * N1);
    float4 a = wr[ln], p = sh4[ln];
    float s = fmaf(a.x, p.x, fmaf(a.y, p.y, fmaf(a.z, p.z, a.w * p.w)));
    if (ln < 11) {
      float4 a2 = wr[64 + ln], p2 = sh4[64 + ln];
      s = fmaf(a2.x, p2.x, fmaf(a2.y, p2.y, fmaf(a2.z, p2.z, fmaf(a2.w, p2.w, s))));
    }
#pragma unroll
    for (int off = 32; off > 0; off >>= 1) s += __shfl_xor(s, off, 64);
    if (ln == 0) sl[n] = s + fc2b[n];
  }
  __syncthreads();

  if (wv == 0) {
    float m = fmaxf(fmaxf(sl[ln], sl[ln + 64]), sl[ln + 128]);
    if (ln < 8) m = fmaxf(m, sl[192 + ln]);
#pragma unroll
    for (int off = 32; off > 0; off >>= 1) m = fmaxf(m, __shfl_xor(m, off, 64));
    if (ln == 0) red[0] = m;
  }
  __syncthreads();
  const float mx = red[0];
  if (tid < N2) sl[tid] = expf(sl[tid] - mx);
  __syncthreads();
  if (wv == 0) {
    float s = sl[ln] + sl[ln + 64] + sl[ln + 128] + (ln < 8 ? sl[192 + ln] : 0.f);
#pragma unroll
    for (int off = 32; off > 0; off >>= 1) s += __shfl_xor(s, off, 64);
    if (ln == 0) red[1] = s;
  }
  __syncthreads();
  if (tid < N2) out[(size_t)b * N2 + tid] = sl[tid] / red[1];
}

}  // namespace

extern "C" void kernel_launch(void* const* d_in, const int* in_sizes, int n_in,
                              void* d_out, int out_size, void* d_ws, size_t ws_size,
                              hipStream_t stream) {
  const float* x     = (const float*)d_in[0];
  const float* w1    = (const float*)d_in[1];
  const float* b1    = (const float*)d_in[2];
  const float* w2    = (const float*)d_in[3];
  const float* b2    = (const float*)d_in[4];
  const float* fc1_w = (const float*)d_in[5];
  const float* fc1_b = (const float*)d_in[6];
  const float* fc2_w = (const float*)d_in[7];
  const float* fc2_b = (const float*)d_in[8];
  float* out = (float*)d_out;

  float* ws  = (float*)d_ws;
  float* w2t = ws;                                  //   599,040 f
  float* h1t = w2t + (size_t)O2 * P2 * HW2;         // 4,866,048 f  (O,HW,B)
  float* h2  = h1t + (size_t)BATCH * O1 * HW1;      //   532,480 f

  wt2_kernel<<<(P2 * HW2 + 255) / 256, 256, 0, stream>>>(w2, w2t);
  lc1_kernel<<<dim3((HW1 + THW - 1) / THW, BATCH / NBB), 512, 0, stream>>>(x, w1, b1, h1t);
  lc2_kernel<<<dim3(HW2, 4), 256, 0, stream>>>(h1t, w2t, b2, h2);
  head_kernel<<<BATCH, 512, 0, stream>>>(h2, fc1_w, fc1_b, fc2_w, fc2_b, out);
}